// Round 1
// baseline (482.954 us; speedup 1.0000x reference)
//
#include <hip/hip_runtime.h>
#include <math.h>

#define BATCH    32
#define FH       64
#define FW       64
#define NA       9
#define NSCORE   (FH*FW*NA)   // 36864 contiguous fg scores per batch
#define TOPN     300
#define SD       16
#define EQ_CAP   256
#define SORTN    512
#define NTHREADS 1024

// 9 base anchors (ratio-major, scale-minor), all centered at (8,8) in the
// (x1 + 0.5*w) convention used by the reference box transform.
__constant__ float c_aw[NA] = {92.f,184.f,368.f,64.f,128.f,256.f,44.f,88.f,176.f};
__constant__ float c_ah[NA] = {48.f,96.f,192.f,64.f,128.f,256.f,88.f,176.f,352.f};

__device__ __forceinline__ unsigned f2key(float f) {
    unsigned u = __float_as_uint(f);
    return (u & 0x80000000u) ? ~u : (u | 0x80000000u);
}
__device__ __forceinline__ float key2f(unsigned k) {
    unsigned u = (k & 0x80000000u) ? (k & 0x7FFFFFFFu) : ~k;
    return __uint_as_float(u);
}

__global__ __launch_bounds__(NTHREADS)
void proposal_topk_kernel(const float* __restrict__ scores_in,
                          const float* __restrict__ bbox,
                          const float* __restrict__ im_info,
                          float* __restrict__ out)
{
    const int b   = blockIdx.x;
    const int tid = threadIdx.x;
    // fg scores: channels 9..17 of (B,18,64,64) — contiguous 36864 floats.
    const float* sc = scores_in + ((size_t)b * 18 + NA) * (FH * FW);

    __shared__ unsigned bins[256];
    __shared__ unsigned sel_key[SORTN];
    __shared__ unsigned sel_idx[SORTN];
    __shared__ unsigned long long sel64[SORTN];
    __shared__ unsigned eq_idx[EQ_CAP];
    __shared__ unsigned s_digit, s_above;
    __shared__ unsigned n_gt, n_eq;

    // ---------- exact radix select (MSB-first, 8-bit digits) ----------
    unsigned prefix = 0u, mask = 0u;
    int K = TOPN;                      // slots still to fill
    for (int shift = 24; shift >= 0; shift -= 8) {
        if (tid < 256) bins[tid] = 0u;
        __syncthreads();
        for (int j = tid; j < NSCORE; j += NTHREADS) {
            unsigned k = f2key(sc[j]);
            if ((k & mask) == prefix)
                atomicAdd(&bins[(k >> shift) & 255u], 1u);
        }
        __syncthreads();
        if (tid == 0) {
            unsigned cum = 0u;
            for (int d = 255; d >= 0; --d) {
                unsigned c = bins[d];
                if (cum + c >= (unsigned)K) { s_digit = (unsigned)d; s_above = cum; break; }
                cum += c;
            }
        }
        __syncthreads();
        prefix |= (s_digit << shift);
        mask   |= (0xFFu << shift);
        K -= (int)s_above;             // slots consumed by strictly-greater digits
        __syncthreads();
    }
    const unsigned T     = prefix;     // exact threshold key
    const int      K_rem = K;          // #elements equal to T to take (lowest idx first)

    // ---------- collection ----------
    if (tid == 0) { n_gt = 0u; n_eq = 0u; }
    for (int j = tid; j < EQ_CAP; j += NTHREADS) eq_idx[j] = 0xFFFFFFFFu;
    if (tid < SORTN) { sel_key[tid] = 0u; sel_idx[tid] = 0xFFFFFFFFu; }
    __syncthreads();
    for (int j = tid; j < NSCORE; j += NTHREADS) {
        unsigned k = f2key(sc[j]);
        if (k < T) continue;
        // flat score position j = a*4096 + (y*64+x)  ->  proposal idx = pos*9 + a
        unsigned a   = (unsigned)j >> 12;
        unsigned pos = (unsigned)j & 4095u;
        unsigned idx = pos * NA + a;
        if (k > T) {
            unsigned p = atomicAdd(&n_gt, 1u);
            sel_key[p] = k; sel_idx[p] = idx;
        } else {
            unsigned q = atomicAdd(&n_eq, 1u);
            if (q < EQ_CAP) eq_idx[q] = idx;
        }
    }
    __syncthreads();

    // sort equal-threshold indices ascending (ties -> lowest index, like lax.top_k)
    for (unsigned ksz = 2; ksz <= EQ_CAP; ksz <<= 1) {
        for (unsigned js = ksz >> 1; js > 0; js >>= 1) {
            for (unsigned i = tid; i < EQ_CAP; i += NTHREADS) {
                unsigned ixj = i ^ js;
                if (ixj > i) {
                    bool up = ((i & ksz) == 0);   // ascending run
                    unsigned x = eq_idx[i], y = eq_idx[ixj];
                    if (up ? (x > y) : (x < y)) { eq_idx[i] = y; eq_idx[ixj] = x; }
                }
            }
            __syncthreads();
        }
    }
    if (tid < (unsigned)K_rem) {
        sel_key[n_gt + tid] = T;
        sel_idx[n_gt + tid] = eq_idx[tid];
    }
    __syncthreads();

    // ---------- final sort: (score desc, idx asc) via composite key ----------
    if (tid < SORTN)
        sel64[tid] = ((unsigned long long)sel_key[tid] << 32) | (unsigned)(~sel_idx[tid]);
    __syncthreads();
    for (unsigned ksz = 2; ksz <= SORTN; ksz <<= 1) {
        for (unsigned js = ksz >> 1; js > 0; js >>= 1) {
            if (tid < SORTN) {
                unsigned i = tid, ixj = i ^ js;
                if (ixj > i) {
                    bool desc = ((i & ksz) == 0);
                    unsigned long long x = sel64[i], y = sel64[ixj];
                    if (desc ? (x < y) : (x > y)) { sel64[i] = y; sel64[ixj] = x; }
                }
            }
            __syncthreads();
        }
    }

    // ---------- decode + write only the 300 winners ----------
    const float xmax = im_info[b * 3 + 1] - 1.0f;
    const float ymax = im_info[b * 3 + 0] - 1.0f;
    float* ob = out + (size_t)b * TOPN * 66;
    for (int item = tid; item < TOPN * SD; item += NTHREADS) {
        int r = item >> 4;          // proposal rank
        int t = item & 15;          // timestep
        unsigned long long e = sel64[r];
        unsigned idx  = ~(unsigned)e;
        float  score  = key2f((unsigned)(e >> 32));
        unsigned a    = idx % 9u;
        unsigned pos  = idx / 9u;
        unsigned x    = pos & 63u;
        unsigned y    = pos >> 6;
        float w  = c_aw[a], h = c_ah[a];
        float cx = 8.0f + 16.0f * (float)x;
        float cy = 8.0f + 16.0f * (float)y;
        const float* dp = bbox + (((size_t)b * 576 + (size_t)(a * 64 + t * 4)) << 12) + pos;
        float d0 = dp[0];
        float d1 = dp[4096];
        float d2 = dp[8192];
        float d3 = dp[12288];
        float pcx = d0 * w + cx;
        float pcy = d1 * h + cy;
        float pw  = expf(d2) * w;
        float ph  = expf(d3) * h;
        float x1 = fminf(fmaxf(pcx - 0.5f * pw, 0.0f), xmax);
        float y1 = fminf(fmaxf(pcy - 0.5f * ph, 0.0f), ymax);
        float x2 = fminf(fmaxf(pcx + 0.5f * pw, 0.0f), xmax);
        float y2 = fminf(fmaxf(pcy + 0.5f * ph, 0.0f), ymax);
        float* orow = ob + r * 66;
        orow[1 + t * 4 + 0] = x1;
        orow[1 + t * 4 + 1] = y1;
        orow[1 + t * 4 + 2] = x2;
        orow[1 + t * 4 + 3] = y2;
        if (t == 0) { orow[0] = (float)b; orow[65] = score; }
    }
}

extern "C" void kernel_launch(void* const* d_in, const int* in_sizes, int n_in,
                              void* d_out, int out_size, void* d_ws, size_t ws_size,
                              hipStream_t stream) {
    const float* scores_in = (const float*)d_in[0];
    const float* bbox      = (const float*)d_in[1];
    const float* im_info   = (const float*)d_in[2];
    // d_in[3] = post_nms_topN (fixed 300, compiled in)
    float* out = (float*)d_out;
    proposal_topk_kernel<<<BATCH, NTHREADS, 0, stream>>>(scores_in, bbox, im_info, out);
}

// Round 2
// 409.635 us; speedup vs baseline: 1.1790x; 1.1790x over previous
//
#include <hip/hip_runtime.h>
#include <math.h>

#define BATCH    32
#define FH       64
#define FW       64
#define NA       9
#define NSCORE   (FH*FW*NA)   // 36864 contiguous fg scores per batch
#define TOPN     300
#define SD       16
#define NTHREADS 1024
#define NBINS    16384        // 14-bit digit
#define NWORDS   (NBINS/2)    // packed 2x16-bit counts
#define CAND_CAP 1024

// 9 base anchors (ratio-major, scale-minor), all centered at (8,8) in the
// (x1 + 0.5*w) convention used by the reference box transform.
__constant__ float c_aw[NA] = {92.f,184.f,368.f,64.f,128.f,256.f,44.f,88.f,176.f};
__constant__ float c_ah[NA] = {48.f,96.f,192.f,64.f,128.f,256.f,88.f,176.f,352.f};

__device__ __forceinline__ unsigned f2key(float f) {
    unsigned u = __float_as_uint(f);
    return (u & 0x80000000u) ? ~u : (u | 0x80000000u);
}
__device__ __forceinline__ float key2f(unsigned k) {
    unsigned u = (k & 0x80000000u) ? (k & 0x7FFFFFFFu) : ~k;
    return __uint_as_float(u);
}

__global__ __launch_bounds__(NTHREADS)
void proposal_topk_kernel(const float* __restrict__ scores_in,
                          const float* __restrict__ bbox,
                          const float* __restrict__ im_info,
                          float* __restrict__ out)
{
    const int b   = blockIdx.x;
    const int tid = threadIdx.x;
    // fg scores: channels 9..17 of (B,18,64,64) — contiguous 36864 floats, 16B-aligned.
    const float* sc = scores_in + ((size_t)b * 18 + NA) * (FH * FW);
    const float4* sc4 = (const float4*)sc;

    __shared__ unsigned hist[NWORDS];            // 32 KB: 16384 bins, 2x16-bit packed
    __shared__ unsigned pscan[NTHREADS];         // 4 KB
    __shared__ unsigned long long cand[CAND_CAP];// 8 KB
    __shared__ unsigned s_t14, s_nsel;

    // ---------- pass A: 14-bit-digit histogram (single global read) ----------
    for (int i = tid; i < NWORDS; i += NTHREADS) hist[i] = 0u;
    __syncthreads();
    for (int j = tid; j < NSCORE / 4; j += NTHREADS) {
        float4 v = sc4[j];
        unsigned d0 = f2key(v.x) >> 18;
        unsigned d1 = f2key(v.y) >> 18;
        unsigned d2 = f2key(v.z) >> 18;
        unsigned d3 = f2key(v.w) >> 18;
        atomicAdd(&hist[d0 >> 1], 1u << ((d0 & 1u) << 4));
        atomicAdd(&hist[d1 >> 1], 1u << ((d1 & 1u) << 4));
        atomicAdd(&hist[d2 >> 1], 1u << ((d2 & 1u) << 4));
        atomicAdd(&hist[d3 >> 1], 1u << ((d3 & 1u) << 4));
    }
    __syncthreads();

    // ---------- find threshold bin: suffix scan over 16384 bins ----------
    // thread t owns bins [t*16, t*16+16)  == words [t*8, t*8+8)
    unsigned w[8];
    unsigned local = 0u;
    #pragma unroll
    for (int i = 0; i < 8; ++i) {
        w[i] = hist[tid * 8 + i];
        local += (w[i] & 0xFFFFu) + (w[i] >> 16);
    }
    pscan[tid] = local;
    __syncthreads();
    // Hillis-Steele inclusive SUFFIX scan: pscan[t] = sum over t' >= t
    for (int off = 1; off < NTHREADS; off <<= 1) {
        unsigned v = pscan[tid];
        unsigned add = (tid + off < NTHREADS) ? pscan[tid + off] : 0u;
        __syncthreads();
        pscan[tid] = v + add;
        __syncthreads();
    }
    unsigned above_excl = (tid + 1 < NTHREADS) ? pscan[tid + 1] : 0u;
    if (above_excl < TOPN && above_excl + local >= TOPN) {   // unique thread
        unsigned cum = above_excl;
        for (int bi = 15; bi >= 0; --bi) {
            unsigned word = w[bi >> 1];
            unsigned c = (bi & 1) ? (word >> 16) : (word & 0xFFFFu);
            if (cum + c >= TOPN) { s_t14 = (unsigned)tid * 16u + (unsigned)bi; break; }
            cum += c;
        }
        s_nsel = 0u;
    }
    __syncthreads();
    const unsigned T14 = s_t14;

    // ---------- pass B: collect all elements in bins >= T14 ----------
    for (int i = tid; i < CAND_CAP; i += NTHREADS) cand[i] = 0ull;
    __syncthreads();
    for (int j4 = tid; j4 < NSCORE / 4; j4 += NTHREADS) {
        float4 v = sc4[j4];
        #pragma unroll
        for (int c = 0; c < 4; ++c) {
            float f = (c == 0) ? v.x : (c == 1) ? v.y : (c == 2) ? v.z : v.w;
            unsigned k = f2key(f);
            if ((k >> 18) >= T14) {
                int j = j4 * 4 + c;
                unsigned a   = (unsigned)j >> 12;       // score chan within fg block
                unsigned pos = (unsigned)j & 4095u;     // y*64+x
                unsigned idx = pos * NA + a;            // proposal index
                unsigned p = atomicAdd(&s_nsel, 1u);
                if (p < CAND_CAP)
                    cand[p] = ((unsigned long long)k << 32) | (unsigned)(~idx);
            }
        }
    }
    __syncthreads();

    // ---------- bitonic sort 1024 descending: (score desc, idx asc) ----------
    for (unsigned ksz = 2; ksz <= CAND_CAP; ksz <<= 1) {
        for (unsigned js = ksz >> 1; js > 0; js >>= 1) {
            unsigned i = (unsigned)tid, ixj = i ^ js;
            if (ixj > i) {
                bool desc = ((i & ksz) == 0);
                unsigned long long x = cand[i], y = cand[ixj];
                if (desc ? (x < y) : (x > y)) { cand[i] = y; cand[ixj] = x; }
            }
            __syncthreads();
        }
    }

    // ---------- decode + write the 300 winners ----------
    const float xmax = im_info[b * 3 + 1] - 1.0f;
    const float ymax = im_info[b * 3 + 0] - 1.0f;
    float* ob = out + (size_t)b * TOPN * 66;
    for (int item = tid; item < TOPN * SD; item += NTHREADS) {
        int r = item >> 4;          // proposal rank
        int t = item & 15;          // timestep
        unsigned long long e = cand[r];
        unsigned idx  = ~(unsigned)e;
        float  score  = key2f((unsigned)(e >> 32));
        unsigned a    = idx % 9u;
        unsigned pos  = idx / 9u;
        unsigned x    = pos & 63u;
        unsigned y    = pos >> 6;
        float w_  = c_aw[a], h_ = c_ah[a];
        float cx = 8.0f + 16.0f * (float)x;
        float cy = 8.0f + 16.0f * (float)y;
        const float* dp = bbox + (((size_t)b * 576 + (size_t)(a * 64 + t * 4)) << 12) + pos;
        float d0 = dp[0];
        float d1 = dp[4096];
        float d2 = dp[8192];
        float d3 = dp[12288];
        float pcx = d0 * w_ + cx;
        float pcy = d1 * h_ + cy;
        float pw  = expf(d2) * w_;
        float ph  = expf(d3) * h_;
        float x1 = fminf(fmaxf(pcx - 0.5f * pw, 0.0f), xmax);
        float y1 = fminf(fmaxf(pcy - 0.5f * ph, 0.0f), ymax);
        float x2 = fminf(fmaxf(pcx + 0.5f * pw, 0.0f), xmax);
        float y2 = fminf(fmaxf(pcy + 0.5f * ph, 0.0f), ymax);
        float* orow = ob + r * 66;
        orow[1 + t * 4 + 0] = x1;
        orow[1 + t * 4 + 1] = y1;
        orow[1 + t * 4 + 2] = x2;
        orow[1 + t * 4 + 3] = y2;
        if (t == 0) { orow[0] = (float)b; orow[65] = score; }
    }
}

extern "C" void kernel_launch(void* const* d_in, const int* in_sizes, int n_in,
                              void* d_out, int out_size, void* d_ws, size_t ws_size,
                              hipStream_t stream) {
    const float* scores_in = (const float*)d_in[0];
    const float* bbox      = (const float*)d_in[1];
    const float* im_info   = (const float*)d_in[2];
    // d_in[3] = post_nms_topN (fixed 300, compiled in)
    float* out = (float*)d_out;
    proposal_topk_kernel<<<BATCH, NTHREADS, 0, stream>>>(scores_in, bbox, im_info, out);
}

// Round 3
// 372.161 us; speedup vs baseline: 1.2977x; 1.1007x over previous
//
#include <hip/hip_runtime.h>
#include <math.h>

#define BATCH    32
#define FH       64
#define FW       64
#define NA       9
#define NSCORE   (FH*FW*NA)   // 36864 contiguous fg scores per batch
#define NVEC     (NSCORE/4)   // 9216 float4s
#define VPT      (NVEC/1024)  // 9 float4 per thread
#define TOPN     300
#define SD       16
#define NTHREADS 1024
#define NBINS    16384        // 14-bit digit
#define NWORDS   (NBINS/2)    // packed 2x16-bit counts
#define CAND_CAP 2048
#define RB       19           // ceil(300/16) r-chunks per batch in decode kernel

// 9 base anchors (ratio-major, scale-minor), all centered at (8,8) in the
// (x1 + 0.5*w) convention used by the reference box transform.
__constant__ float c_aw[NA] = {92.f,184.f,368.f,64.f,128.f,256.f,44.f,88.f,176.f};
__constant__ float c_ah[NA] = {48.f,96.f,192.f,64.f,128.f,256.f,88.f,176.f,352.f};

__device__ __forceinline__ unsigned f2key(float f) {
    unsigned u = __float_as_uint(f);
    return (u & 0x80000000u) ? ~u : (u | 0x80000000u);
}
__device__ __forceinline__ float key2f(unsigned k) {
    unsigned u = (k & 0x80000000u) ? (k & 0x7FFFFFFFu) : ~k;
    return __uint_as_float(u);
}

// ---------------- K1: exact top-300 select per batch ----------------
__global__ __launch_bounds__(NTHREADS)
void topk_kernel(const float* __restrict__ scores_in,
                 unsigned long long* __restrict__ sel)   // [BATCH][TOPN]
{
    const int b    = blockIdx.x;
    const int tid  = threadIdx.x;
    const int lane = tid & 63;
    const int wv   = tid >> 6;          // 16 waves
    const float4* sc4 = (const float4*)(scores_in + ((size_t)b * 18 + NA) * (FH * FW));

    __shared__ unsigned hist[NWORDS];             // 32 KB
    __shared__ unsigned long long cand[CAND_CAP]; // 16 KB
    __shared__ unsigned wtot[16], wsuf[16];
    __shared__ unsigned s_t14, s_nsel;

    // pass A: histogram over 14-bit digits; cache scores in registers
    for (int i = tid; i < NWORDS; i += NTHREADS) hist[i] = 0u;
    if (tid == 0) s_nsel = 0u;
    __syncthreads();
    float4 v[VPT];
    #pragma unroll
    for (int k = 0; k < VPT; ++k) {
        v[k] = sc4[tid + k * NTHREADS];
        unsigned d0 = f2key(v[k].x) >> 18;
        unsigned d1 = f2key(v[k].y) >> 18;
        unsigned d2 = f2key(v[k].z) >> 18;
        unsigned d3 = f2key(v[k].w) >> 18;
        atomicAdd(&hist[d0 >> 1], 1u << ((d0 & 1u) << 4));
        atomicAdd(&hist[d1 >> 1], 1u << ((d1 & 1u) << 4));
        atomicAdd(&hist[d2 >> 1], 1u << ((d2 & 1u) << 4));
        atomicAdd(&hist[d3 >> 1], 1u << ((d3 & 1u) << 4));
    }
    __syncthreads();

    // threshold bin via wave-shuffle suffix scan (thread owns bins [t*16,t*16+16))
    unsigned w[8];
    unsigned local = 0u;
    #pragma unroll
    for (int i = 0; i < 8; ++i) {
        w[i] = hist[tid * 8 + i];
        local += (w[i] & 0xFFFFu) + (w[i] >> 16);
    }
    unsigned incl = local;                       // inclusive suffix within wave
    #pragma unroll
    for (int off = 1; off < 64; off <<= 1) {
        unsigned o = __shfl_down(incl, off);
        if (lane + off < 64) incl += o;
    }
    if (lane == 0) wtot[wv] = incl;              // wave total
    __syncthreads();
    if (tid < 16) {                              // suffix-exclusive over 16 wave totals
        unsigned x = wtot[tid];
        #pragma unroll
        for (int off = 1; off < 16; off <<= 1) {
            unsigned o = __shfl_down(x, off, 16);
            if ((tid & 15) + off < 16) x += o;
        }
        wsuf[tid] = x - wtot[tid];               // sum over waves > tid
    }
    __syncthreads();
    unsigned above_excl = wsuf[wv] + (incl - local);   // count in bins above my range
    if (above_excl < TOPN && above_excl + local >= TOPN) {   // unique thread
        unsigned cum = above_excl;
        for (int bi = 15; bi >= 0; --bi) {
            unsigned word = w[bi >> 1];
            unsigned c = (bi & 1) ? (word >> 16) : (word & 0xFFFFu);
            if (cum + c >= TOPN) { s_t14 = (unsigned)tid * 16u + (unsigned)bi; break; }
            cum += c;
        }
    }
    __syncthreads();
    const unsigned T14 = s_t14;

    // pass B: collect candidates from the register cache (no global re-read)
    #pragma unroll
    for (int k = 0; k < VPT; ++k) {
        #pragma unroll
        for (int c = 0; c < 4; ++c) {
            float f = (c == 0) ? v[k].x : (c == 1) ? v[k].y : (c == 2) ? v[k].z : v[k].w;
            unsigned key = f2key(f);
            if ((key >> 18) >= T14) {
                int j = (tid + k * NTHREADS) * 4 + c;
                unsigned a   = (unsigned)j >> 12;
                unsigned pos = (unsigned)j & 4095u;
                unsigned idx = pos * NA + a;
                unsigned p = atomicAdd(&s_nsel, 1u);
                if (p < CAND_CAP)
                    cand[p] = ((unsigned long long)key << 32) | (unsigned)(~idx);
            }
        }
    }
    __syncthreads();

    // exact rank: composite keys are unique -> ranks unique. Lockstep LDS broadcast.
    unsigned n = s_nsel; if (n > CAND_CAP) n = CAND_CAP;
    if (tid < (int)n) {
        unsigned long long my = cand[tid];
        unsigned rank = 0;
        for (unsigned j = 0; j < n; ++j) rank += (cand[j] > my);
        if (rank < TOPN) sel[(size_t)b * TOPN + rank] = my;
    }
}

// ---------------- K2: decode + write the winners (full-chip) ----------------
__global__ __launch_bounds__(256)
void decode_kernel(const float* __restrict__ bbox,
                   const float* __restrict__ im_info,
                   const unsigned long long* __restrict__ sel,
                   float* __restrict__ out)
{
    const int b     = blockIdx.x / RB;
    const int chunk = blockIdx.x % RB;
    const int tid   = threadIdx.x;
    const int r     = chunk * 16 + (tid >> 4);
    const int t     = tid & 15;
    if (r >= TOPN) return;

    unsigned long long e = sel[(size_t)b * TOPN + r];
    unsigned idx  = ~(unsigned)e;
    float  score  = key2f((unsigned)(e >> 32));
    unsigned a    = idx % 9u;
    unsigned pos  = idx / 9u;
    unsigned x    = pos & 63u;
    unsigned y    = pos >> 6;
    float w_ = c_aw[a], h_ = c_ah[a];
    float cx = 8.0f + 16.0f * (float)x;
    float cy = 8.0f + 16.0f * (float)y;
    const float* dp = bbox + (((size_t)b * 576 + (size_t)(a * 64 + t * 4)) << 12) + pos;
    float d0 = dp[0];
    float d1 = dp[4096];
    float d2 = dp[8192];
    float d3 = dp[12288];
    float xmax = im_info[b * 3 + 1] - 1.0f;
    float ymax = im_info[b * 3 + 0] - 1.0f;
    float pcx = d0 * w_ + cx;
    float pcy = d1 * h_ + cy;
    float pw  = expf(d2) * w_;
    float ph  = expf(d3) * h_;
    float x1 = fminf(fmaxf(pcx - 0.5f * pw, 0.0f), xmax);
    float y1 = fminf(fmaxf(pcy - 0.5f * ph, 0.0f), ymax);
    float x2 = fminf(fmaxf(pcx + 0.5f * pw, 0.0f), xmax);
    float y2 = fminf(fmaxf(pcy + 0.5f * ph, 0.0f), ymax);
    float* orow = out + ((size_t)b * TOPN + r) * 66;
    orow[1 + t * 4 + 0] = x1;
    orow[1 + t * 4 + 1] = y1;
    orow[1 + t * 4 + 2] = x2;
    orow[1 + t * 4 + 3] = y2;
    if (t == 0) { orow[0] = (float)b; orow[65] = score; }
}

extern "C" void kernel_launch(void* const* d_in, const int* in_sizes, int n_in,
                              void* d_out, int out_size, void* d_ws, size_t ws_size,
                              hipStream_t stream) {
    const float* scores_in = (const float*)d_in[0];
    const float* bbox      = (const float*)d_in[1];
    const float* im_info   = (const float*)d_in[2];
    // d_in[3] = post_nms_topN (fixed 300, compiled in)
    float* out = (float*)d_out;
    unsigned long long* sel = (unsigned long long*)d_ws;   // 32*300*8 = 76.8 KB

    topk_kernel<<<BATCH, NTHREADS, 0, stream>>>(scores_in, sel);
    decode_kernel<<<BATCH * RB, 256, 0, stream>>>(bbox, im_info, sel, out);
}